// Round 11
// baseline (204.131 us; speedup 1.0000x reference)
//
#include <hip/hip_runtime.h>
#include <cstddef>

constexpr int Bc = 2, Sc = 2048, Hc = 16, Dc = 64, HIDc = 1024;
#define NEG_INF -10000.0f

typedef _Float16 half8  __attribute__((ext_vector_type(8)));  // K=32 MFMA A/B frag
typedef _Float16 half4  __attribute__((ext_vector_type(4)));  // K=16 MFMA A/B frag
typedef float   floatx4 __attribute__((ext_vector_type(4)));  // MFMA C/D frag

// workspace layout (bytes)
#define OFF_AD 0u                                  // adder: 2*2048 f32 (16 KB, pad 64K)
#define OFF_XH (64u * 1024)                        // xh: 8 MB
#define OFF_WT (OFF_XH + 8u * 1024 * 1024)         // Wt: 6 MB
#define OFF_QW (OFF_WT + 6u * 1024 * 1024)         // qw: 8 MB
#define OFF_KW (OFF_QW + 8u * 1024 * 1024)         // kw: 8 MB
#define OFF_VT (OFF_KW + 8u * 1024 * 1024)         // vt: 8 MB
#define OFF_PO (OFF_VT + 8u * 1024 * 1024)         // part_o: 2*32*2048*64 f32 = 32 MB
#define OFF_PL (OFF_PO + 32u * 1024 * 1024)        // part_l: 2*32*2048 f32 = 512 KB
#define WS_NEED ((size_t)OFF_PL + 512u * 1024)

// ---------------------------------------------------------------------------
// cvt (fused): z<3 -> W transpose fp32[k][n] -> f16[n][k]; z==3 -> x fp32->f16
// (and, for by==0, the additive-mask table into ws).
// ---------------------------------------------------------------------------
__global__ __launch_bounds__(256) void cvt_kernel(
    const float* __restrict__ x, const int* __restrict__ mask,
    const float* __restrict__ Wq, const float* __restrict__ Wk,
    const float* __restrict__ Wv,
    _Float16* __restrict__ xh, _Float16* __restrict__ Wt,
    float* __restrict__ adder_g)
{
    const int t = threadIdx.x;
    const int z = blockIdx.z;
    if (z < 3) {
        const float* W = (z == 0) ? Wq : (z == 1) ? Wk : Wv;
        _Float16* out = Wt + (size_t)z * HIDc * HIDc;
        __shared__ _Float16 T[64][65];
        const int kb = blockIdx.x * 64, nb = blockIdx.y * 64;
        const int r = t >> 2, c4 = (t & 3) * 16;
        #pragma unroll
        for (int i = 0; i < 16; i += 4) {
            float4 a = *(const float4*)(W + (size_t)(kb + r) * HIDc + nb + c4 + i);
            T[c4 + i + 0][r] = (_Float16)a.x;
            T[c4 + i + 1][r] = (_Float16)a.y;
            T[c4 + i + 2][r] = (_Float16)a.z;
            T[c4 + i + 3][r] = (_Float16)a.w;
        }
        __syncthreads();
        const int n = t >> 2, k4 = (t & 3) * 16;
        half8 o0, o1;
        #pragma unroll
        for (int j = 0; j < 8; ++j) { o0[j] = T[n][k4 + j]; o1[j] = T[n][k4 + 8 + j]; }
        *(half8*)(out + (size_t)(nb + n) * HIDc + kb + k4)     = o0;
        *(half8*)(out + (size_t)(nb + n) * HIDc + kb + k4 + 8) = o1;
    } else {
        // x conversion: 256 blocks x 16384 contiguous elements
        const int cid = blockIdx.y * 16 + blockIdx.x;
        const int base = cid * 16384;
        #pragma unroll
        for (int i = 0; i < 8; ++i) {
            const int idx = base + i * 2048 + t * 8;
            float4 a = *(const float4*)(x + idx);
            float4 b = *(const float4*)(x + idx + 4);
            half8 h;
            h[0] = (_Float16)a.x; h[1] = (_Float16)a.y; h[2] = (_Float16)a.z; h[3] = (_Float16)a.w;
            h[4] = (_Float16)b.x; h[5] = (_Float16)b.y; h[6] = (_Float16)b.z; h[7] = (_Float16)b.w;
            *(half8*)(xh + idx) = h;
        }
        if (blockIdx.y == 0) {   // adder: 16 blocks x 256 = 4096 entries
            const int idx = blockIdx.x * 256 + t;      // = bI*Sc + s
            adder_g[idx] = (1.0f - (float)mask[idx]) * NEG_INF;
        }
    }
}

// ---------------------------------------------------------------------------
// proj: byte-identical to R10 (passing). Single-barrier LDS double-buffer
// pipeline; 128x128 tile, BK=32, 4 waves x (64x64).
// ---------------------------------------------------------------------------
#define PSTR 40
__global__ __launch_bounds__(256, 2) void proj_kernel(
    const _Float16* __restrict__ xh, const _Float16* __restrict__ Wt,
    const float* __restrict__ bq, const float* __restrict__ bk, const float* __restrict__ bv,
    _Float16* __restrict__ qw, _Float16* __restrict__ kw, _Float16* __restrict__ vt)
{
    const int z = blockIdx.z;
    const _Float16* Wz = Wt + (size_t)z * HIDc * HIDc;
    const float* bias = (z == 0) ? bq : (z == 1) ? bk : bv;

    __shared__ _Float16 As[2][128 * PSTR];
    __shared__ _Float16 Bs[2][128 * PSTR];

    const int t = threadIdx.x;
    const int lane = t & 63, w = t >> 6;
    const int quad = lane >> 4, l16 = lane & 15;
    const int m0 = blockIdx.y * 128, n0 = blockIdx.x * 128;
    const int wm = (w >> 1) * 64, wn = (w & 1) * 64;
    const int sr = t >> 1, sh = (t & 1) * 16;

    floatx4 acc[4][4];
    #pragma unroll
    for (int mb = 0; mb < 4; ++mb)
        #pragma unroll
        for (int nb = 0; nb < 4; ++nb) acc[mb][nb] = floatx4{0.f, 0.f, 0.f, 0.f};

    {
        const _Float16* ap = xh + (size_t)(m0 + sr) * HIDc + sh;
        const _Float16* bp = Wz + (size_t)(n0 + sr) * HIDc + sh;
        *(uint4*)(As[0] + sr * PSTR + sh)     = *(const uint4*)(ap);
        *(uint4*)(As[0] + sr * PSTR + sh + 8) = *(const uint4*)(ap + 8);
        *(uint4*)(Bs[0] + sr * PSTR + sh)     = *(const uint4*)(bp);
        *(uint4*)(Bs[0] + sr * PSTR + sh + 8) = *(const uint4*)(bp + 8);
    }
    __syncthreads();

    #pragma unroll 2
    for (int it = 0; it < HIDc / 32; ++it) {
        const int cur = it & 1;
        const int kn = (it + 1 < HIDc / 32) ? (it + 1) * 32 : 0;
        const _Float16* ap = xh + (size_t)(m0 + sr) * HIDc + kn + sh;
        const _Float16* bp = Wz + (size_t)(n0 + sr) * HIDc + kn + sh;
        uint4 a0 = *(const uint4*)(ap);
        uint4 a1 = *(const uint4*)(ap + 8);
        uint4 b0 = *(const uint4*)(bp);
        uint4 b1 = *(const uint4*)(bp + 8);

        half8 af[4], bf[4];
        #pragma unroll
        for (int mb = 0; mb < 4; ++mb)
            af[mb] = *(const half8*)(As[cur] + (wm + mb * 16 + l16) * PSTR + quad * 8);
        #pragma unroll
        for (int nb = 0; nb < 4; ++nb)
            bf[nb] = *(const half8*)(Bs[cur] + (wn + nb * 16 + l16) * PSTR + quad * 8);
        #pragma unroll
        for (int mb = 0; mb < 4; ++mb)
            #pragma unroll
            for (int nb = 0; nb < 4; ++nb)
                acc[mb][nb] = __builtin_amdgcn_mfma_f32_16x16x32_f16(
                    af[mb], bf[nb], acc[mb][nb], 0, 0, 0);

        *(uint4*)(As[cur ^ 1] + sr * PSTR + sh)     = a0;
        *(uint4*)(As[cur ^ 1] + sr * PSTR + sh + 8) = a1;
        *(uint4*)(Bs[cur ^ 1] + sr * PSTR + sh)     = b0;
        *(uint4*)(Bs[cur ^ 1] + sr * PSTR + sh + 8) = b1;
        __syncthreads();
    }

    #pragma unroll
    for (int nb = 0; nb < 4; ++nb) {
        const int N = n0 + wn + nb * 16 + l16;
        const float bi = bias[N];
        const int h = N >> 6, d = N & 63;
        #pragma unroll
        for (int mb = 0; mb < 4; ++mb) {
            #pragma unroll
            for (int r = 0; r < 4; ++r) {
                const int M = m0 + wm + mb * 16 + quad * 4 + r;
                const int bI = M >> 11, s = M & (Sc - 1);
                const float v = acc[mb][nb][r] + bi;
                if (z == 0)
                    qw[(((size_t)(bI * Hc + h)) * Sc + s) * Dc + d] = (_Float16)(v * 0.125f);
                else if (z == 1)
                    kw[(((size_t)(bI * Hc + h)) * Sc + s) * Dc + d] = (_Float16)v;
                else
                    vt[(((size_t)(bI * Hc + h)) * Dc + d) * Sc + s] = (_Float16)v;
            }
        }
    }
}

// ---------------------------------------------------------------------------
// attn R11: zero-shuffle transposed-scores math (R9-verified), restructured
// for TLP: 128-thread blocks (2 waves x 32 q-rows), 32-key tiles, LDS 19.5 KB
// -> up to 8 blocks/CU; grid split over keys (nsplit, exactly additive since
// there is no running max: o_tot = sum o_half, l_tot = sum l_half). Partials
// to ws; combine kernel normalizes. nsplit==1 falls back to direct out write.
// Additive mask read from precomputed global table (L1-resident).
// ---------------------------------------------------------------------------
__global__ __launch_bounds__(128, 3) void attn_kernel(
    const _Float16* __restrict__ qw, const _Float16* __restrict__ kw,
    const _Float16* __restrict__ vt, const float* __restrict__ adder_g,
    float* __restrict__ part_o, float* __restrict__ part_l,
    float* __restrict__ out, int nsplit)
{
    __shared__ __align__(16) _Float16 Ks[2][32][72];   //  9 KB [key][d]
    __shared__ __align__(16) _Float16 Vs[2][64][40];   // 10 KB [d][key]

    const int t = threadIdx.x;
    const int lane = t & 63, w = t >> 6;          // w: 0..1
    const int quad = lane >> 4, l16 = lane & 15;
    const int bh = blockIdx.y;
    const int bI = bh >> 4, h = bh & 15;
    const int half = blockIdx.z;
    const int kt0 = half * (Sc / nsplit);
    const int niter = (Sc / nsplit) / 32;

    const _Float16* Qp = qw + (size_t)bh * Sc * Dc;
    const _Float16* Kp = kw + (size_t)bh * Sc * Dc;
    const _Float16* Vp = vt + (size_t)bh * Dc * Sc;
    const float* adp = adder_g + bI * Sc;

    const int srK = t >> 2, scK = (t & 3) * 16;   // K tile: 32 rows x 64 el
    const int srV = t >> 1, scV = (t & 1) * 16;   // V tile: 64 rows x 32 el

    {   // preload tile 0 into buffer 0
        uint4 k0 = *(const uint4*)(Kp + (size_t)(kt0 + srK) * Dc + scK);
        uint4 k1 = *(const uint4*)(Kp + (size_t)(kt0 + srK) * Dc + scK + 8);
        uint4 v0 = *(const uint4*)(Vp + (size_t)srV * Sc + kt0 + scV);
        uint4 v1 = *(const uint4*)(Vp + (size_t)srV * Sc + kt0 + scV + 8);
        *(uint4*)(&Ks[0][srK][scK])     = k0;
        *(uint4*)(&Ks[0][srK][scK + 8]) = k1;
        *(uint4*)(&Vs[0][srV][scV])     = v0;
        *(uint4*)(&Vs[0][srV][scV + 8]) = v1;
    }

    const int qrow = blockIdx.x * 64 + w * 32;
    half8 aq[2][2];   // Q as B-frag of S^T: B[n=q=l16][k=d=quad*8+j]
    #pragma unroll
    for (int s = 0; s < 2; ++s)
        #pragma unroll
        for (int hh = 0; hh < 2; ++hh)
            aq[s][hh] = *(const half8*)(Qp + (size_t)(qrow + 16 * s + l16) * Dc
                                        + hh * 32 + quad * 8);

    floatx4 o[2][4];
    #pragma unroll
    for (int s = 0; s < 2; ++s)
        #pragma unroll
        for (int db = 0; db < 4; ++db) o[s][db] = floatx4{0.f, 0.f, 0.f, 0.f};
    float lsum[2] = {0.f, 0.f};

    __syncthreads();   // tile 0 visible

    #pragma unroll 2
    for (int it = 0; it < niter; ++it) {
        const int cur = it & 1;
        const int kt = kt0 + it * 32;
        const int ktn = (it + 1 < niter) ? kt + 32 : kt0;
        // ---- issue global loads for next tile
        uint4 k0 = *(const uint4*)(Kp + (size_t)(ktn + srK) * Dc + scK);
        uint4 k1 = *(const uint4*)(Kp + (size_t)(ktn + srK) * Dc + scK + 8);
        uint4 v0 = *(const uint4*)(Vp + (size_t)srV * Sc + ktn + scV);
        uint4 v1 = *(const uint4*)(Vp + (size_t)srV * Sc + ktn + scV + 8);

        // ---- frags from LDS buf[cur]
        half8 kb[2][2];   // A[m=key=l16][k=d=quad*8+j]
        half4 vb[2][4];   // B[n=d=l16][k=key=quad*4+i]
        #pragma unroll
        for (int nb = 0; nb < 2; ++nb)
            #pragma unroll
            for (int hh = 0; hh < 2; ++hh)
                kb[nb][hh] = *(const half8*)(&Ks[cur][nb * 16 + l16][hh * 32 + quad * 8]);
        #pragma unroll
        for (int nb = 0; nb < 2; ++nb)
            #pragma unroll
            for (int db = 0; db < 4; ++db)
                vb[nb][db] = *(const half4*)(&Vs[cur][db * 16 + l16][nb * 16 + quad * 4]);

        // ---- S^T = K @ Q^T : D[m=key][n=q]
        floatx4 st[2][2];
        #pragma unroll
        for (int s = 0; s < 2; ++s)
            #pragma unroll
            for (int nb = 0; nb < 2; ++nb) {
                floatx4 acc = floatx4{0.f, 0.f, 0.f, 0.f};
                acc = __builtin_amdgcn_mfma_f32_16x16x32_f16(kb[nb][0], aq[s][0], acc, 0, 0, 0);
                acc = __builtin_amdgcn_mfma_f32_16x16x32_f16(kb[nb][1], aq[s][1], acc, 0, 0, 0);
                st[s][nb] = acc;
            }

        // ---- P = exp(S^T + mask): registers are directly PV A-frags
        half4 pa[2][2];
        #pragma unroll
        for (int nb = 0; nb < 2; ++nb) {
            const float4 a4 = *(const float4*)&adp[kt + nb * 16 + quad * 4];
            const float ad[4] = {a4.x, a4.y, a4.z, a4.w};
            #pragma unroll
            for (int s = 0; s < 2; ++s)
                #pragma unroll
                for (int r = 0; r < 4; ++r) {
                    const float p = __expf(st[s][nb][r] + ad[r]);
                    lsum[s] += p;
                    pa[s][nb][r] = (_Float16)p;
                }
        }

        // ---- O += P @ V (K=16 MFMA)
        #pragma unroll
        for (int s = 0; s < 2; ++s)
            #pragma unroll
            for (int nb = 0; nb < 2; ++nb)
                #pragma unroll
                for (int db = 0; db < 4; ++db)
                    o[s][db] = __builtin_amdgcn_mfma_f32_16x16x16f16(
                        pa[s][nb], vb[nb][db], o[s][db], 0, 0, 0);

        // ---- stage next tile into buf[cur^1]
        *(uint4*)(&Ks[cur ^ 1][srK][scK])     = k0;
        *(uint4*)(&Ks[cur ^ 1][srK][scK + 8]) = k1;
        *(uint4*)(&Vs[cur ^ 1][srV][scV])     = v0;
        *(uint4*)(&Vs[cur ^ 1][srV][scV + 8]) = v1;
        __syncthreads();
    }

    // ---- denominator totals for q=l16 on every lane
    #pragma unroll
    for (int s = 0; s < 2; ++s) {
        lsum[s] += __shfl_xor(lsum[s], 16, 64);
        lsum[s] += __shfl_xor(lsum[s], 32, 64);
    }

    if (nsplit == 1) {
        float* op = out + (size_t)bI * Sc * HIDc + h * Dc;
        #pragma unroll
        for (int s = 0; s < 2; ++s)
            #pragma unroll
            for (int r = 0; r < 4; ++r) {
                const float inv = 1.0f / __shfl(lsum[s], quad * 4 + r, 64);
                const int q = qrow + 16 * s + quad * 4 + r;
                #pragma unroll
                for (int db = 0; db < 4; ++db)
                    op[(size_t)q * HIDc + db * 16 + l16] = o[s][db][r] * inv;
            }
    } else {
        float* po = part_o + ((size_t)half * 32 + bh) * Sc * Dc;
        #pragma unroll
        for (int s = 0; s < 2; ++s)
            #pragma unroll
            for (int r = 0; r < 4; ++r) {
                const int q = qrow + 16 * s + quad * 4 + r;
                #pragma unroll
                for (int db = 0; db < 4; ++db)
                    po[(size_t)q * Dc + db * 16 + l16] = o[s][db][r];
            }
        if (quad == 0) {
            #pragma unroll
            for (int s = 0; s < 2; ++s)
                part_l[((size_t)half * 32 + bh) * Sc + qrow + 16 * s + l16] = lsum[s];
        }
    }
}

// ---------------------------------------------------------------------------
// combine: out = (oA + oB) / (lA + lB)   (only when nsplit == 2)
// ---------------------------------------------------------------------------
__global__ __launch_bounds__(256) void combine_kernel(
    const float* __restrict__ part_o, const float* __restrict__ part_l,
    float* __restrict__ out)
{
    const int g = blockIdx.x * 256 + threadIdx.x;
    const int d4 = g & 15;
    const int q  = (g >> 4) & (Sc - 1);
    const int bh = g >> 15;
    const int bI = bh >> 4, h = bh & 15;
    const float* poA = part_o + (size_t)bh * Sc * Dc + (size_t)q * Dc + d4 * 4;
    const float* poB = poA + (size_t)32 * Sc * Dc;
    const float lA = part_l[(size_t)bh * Sc + q];
    const float lB = part_l[(size_t)32 * Sc + (size_t)bh * Sc + q];
    const float inv = 1.0f / (lA + lB);
    float4 a = *(const float4*)poA;
    float4 b = *(const float4*)poB;
    float4 r;
    r.x = (a.x + b.x) * inv;
    r.y = (a.y + b.y) * inv;
    r.z = (a.z + b.z) * inv;
    r.w = (a.w + b.w) * inv;
    *(float4*)(out + (size_t)bI * Sc * HIDc + (size_t)q * HIDc + h * Dc + d4 * 4) = r;
}

// ---------------------------------------------------------------------------
extern "C" void kernel_launch(void* const* d_in, const int* in_sizes, int n_in,
                              void* d_out, int out_size, void* d_ws, size_t ws_size,
                              hipStream_t stream) {
    const float* x    = (const float*)d_in[0];
    const int*   mask = (const int*)  d_in[1];
    const float* Wq   = (const float*)d_in[2];
    const float* bq   = (const float*)d_in[3];
    const float* Wk   = (const float*)d_in[4];
    const float* bk   = (const float*)d_in[5];
    const float* Wv   = (const float*)d_in[6];
    const float* bv   = (const float*)d_in[7];
    float* out = (float*)d_out;

    char* ws = (char*)d_ws;
    float*    adder = (float*)   (ws + OFF_AD);
    _Float16* xh    = (_Float16*)(ws + OFF_XH);
    _Float16* Wt    = (_Float16*)(ws + OFF_WT);
    _Float16* qw    = (_Float16*)(ws + OFF_QW);
    _Float16* kw    = (_Float16*)(ws + OFF_KW);
    _Float16* vt    = (_Float16*)(ws + OFF_VT);
    float*    po    = (float*)   (ws + OFF_PO);
    float*    pl    = (float*)   (ws + OFF_PL);

    const int nsplit = (ws_size >= WS_NEED) ? 2 : 1;   // constant per session

    cvt_kernel<<<dim3(16, 16, 4), 256, 0, stream>>>(x, mask, Wq, Wk, Wv, xh, Wt, adder);
    proj_kernel<<<dim3(HIDc / 128, (Bc * Sc) / 128, 3), 256, 0, stream>>>(
        xh, Wt, bq, bk, bv, qw, kw, vt);
    attn_kernel<<<dim3(Sc / 64, Bc * Hc, nsplit), 128, 0, stream>>>(
        qw, kw, vt, adder, po, pl, out, nsplit);
    if (nsplit == 2)
        combine_kernel<<<(Bc * Hc * Sc * Dc / 4) / 256, 256, 0, stream>>>(po, pl, out);
}